// Round 1
// baseline (1064.262 us; speedup 1.0000x reference)
//
#include <hip/hip_runtime.h>
#include <math.h>

// Problem constants (fixed by the reference)
#define BN 256     // batch N
#define TT 1000    // timesteps
#define NO 10      // obs dim
#define NS 10      // state dim
#define HID 64     // GRU hidden == wavefront size
#define DIN 20     // NO + NS
#define G3 192     // 3*HID
#define GS 8       // steps per input group (1000 = 125 * 8)
#define NG 125     // groups

// broadcast lane `l`'s value of v to all lanes (l compile-time/uniform)
__device__ __forceinline__ float bcast(float v, int l) {
    return __int_as_float(__builtin_amdgcn_readlane(__float_as_int(v), l));
}
__device__ __forceinline__ float rcpf(float x) { return __builtin_amdgcn_rcpf(x); }

// ---------------- Phase 1: GRU recurrence, ONE WAVE PER SAMPLE -------------
// R6 theory: the 4-wave k-split pays a ds_write -> barrier -> ds_read_b128
// exchange every timestep (~900 of the ~1240 cyc/step). With HID == 64 one
// wave owns the whole hidden state: lane j computes output unit j, h is
// broadcast via v_readlane (register-only, no LDS, no barrier). Per step:
// 64 x (readlane + 4 fma) + 60 input fmas + nonlinearity ~= 800 cyc, pure
// issue. fp32 pk-fma gains nothing on gfx950 (157.3 TF == non-packed rate),
// so scalar v_fma_f32 is the fp32 issue floor.
// waves_per_eu(1,1): 512-VGPR budget; the 316 weight floats must stay
// register-resident (all array indexing is fully unrolled / constant).
__global__
__attribute__((amdgpu_flat_work_group_size(64, 64), amdgpu_waves_per_eu(1, 1)))
void gru_onewave(const float* __restrict__ Yi, const float* __restrict__ Xh,
                 const float* __restrict__ Wi, const float* __restrict__ Wh,
                 const float* __restrict__ bi, const float* __restrict__ bh,
                 const float* __restrict__ Wmu, const float* __restrict__ Wvar,
                 float* __restrict__ mv_out) {
    const int lane = threadIdx.x;   // hidden unit index
    const int n = blockIdx.x;       // sample

    // input staging: [buf][step][32] floats; y at 0..9, x at 10..19, pad to 32
    // so every step row is 128 B => 16B-aligned float4 broadcast reads.
    // Single wave => DS pipe in-order => no barrier needed between the group
    // staging writes and the per-step broadcast reads.
    __shared__ __align__(16) float inb[2][GS * 32];

    // ---- per-lane weight columns, register-resident ----
    float whr[HID], whz[HID], whn[HID], wmv[HID];
#pragma unroll
    for (int k = 0; k < HID; ++k) {
        whr[k] = Wh[k * G3 + lane];
        whz[k] = Wh[k * G3 + 64 + lane];
        whn[k] = Wh[k * G3 + 128 + lane];
        float wm = 0.0f;
        if (lane < NS) wm = Wmu[k * NS + lane];
        else if (lane < DIN) wm = Wvar[k * NS + (lane - NS)];
        wmv[k] = wm;    // packed: lanes 0..9 -> W_mu, lanes 10..19 -> W_var
    }
    float wir[DIN], wiz[DIN], win[DIN];
#pragma unroll
    for (int d = 0; d < DIN; ++d) {
        wir[d] = Wi[d * G3 + lane];
        wiz[d] = Wi[d * G3 + 64 + lane];
        win[d] = Wi[d * G3 + 128 + lane];
    }
    const float b_r = bi[lane] + bh[lane];
    const float b_z = bi[64 + lane] + bh[64 + lane];
    const float bxn = bi[128 + lane];
    const float bhn = bh[128 + lane];

    const float* yb = Yi + (size_t)n * TT * NO;
    const float* xb = Xh + (size_t)n * TT * NS;
    float* ob = mv_out + (size_t)n * TT * DIN;

    // staging write addresses: flat input idx f -> step f/10, elem f%10
    const int s0 = lane / 10, j0 = lane - 10 * s0;               // f = lane
    const int s1 = (64 + lane) / 10, j1 = (64 + lane) - 10 * s1; // f = 64+lane
    const int wy0 = s0 * 32 + j0, wx0 = wy0 + 10;
    const int wy1 = s1 * 32 + j1, wx1 = wy1 + 10;

    // prologue: group 0 loads into registers
    float ly0 = yb[lane], lx0 = xb[lane];
    float ly1 = 0.0f, lx1 = 0.0f;
    if (lane < 16) { ly1 = yb[64 + lane]; lx1 = xb[64 + lane]; }

    float h = 0.0f;

#pragma unroll 1
    for (int g = 0; g < NG; ++g) {
        float* buf = inb[g & 1];
        // stage current group (writes precede this group's reads; DS in-order)
        buf[wy0] = ly0; buf[wx0] = lx0;
        if (lane < 16) { buf[wy1] = ly1; buf[wx1] = lx1; }
        // prefetch next group; 8 steps (~6k cycles) of latency cover
        if (g + 1 < NG) {
            const size_t o = (size_t)(g + 1) * (GS * NO);
            ly0 = yb[o + lane]; lx0 = xb[o + lane];
            if (lane < 16) { ly1 = yb[o + 64 + lane]; lx1 = xb[o + 64 + lane]; }
        }

#pragma unroll 2
        for (int s = 0; s < GS; ++s) {
            // x_t broadcast: 5 same-address ds_read_b128 (conflict-free)
            const float4* qp = (const float4*)(buf + s * 32);
            const float4 q0 = qp[0], q1 = qp[1], q2 = qp[2], q3 = qp[3], q4 = qp[4];

            float ar = b_r, az = b_z, ax = bxn, ah = bhn, am = 0.0f;

            // hidden projection: h_{t-1} broadcast via readlane, 4 fma per k
            // (am accumulates amv for output t-1 -- packed W_mu/W_var column)
#pragma unroll
            for (int k = 0; k < HID; ++k) {
                const float hv = bcast(h, k);
                ar = fmaf(hv, whr[k], ar);
                az = fmaf(hv, whz[k], az);
                ah = fmaf(hv, whn[k], ah);
                am = fmaf(hv, wmv[k], am);
            }

            // input projection (values broadcast-identical across lanes)
#define IN3(d, val) { const float xv_ = (val);              \
            ar = fmaf(xv_, wir[d], ar);                     \
            az = fmaf(xv_, wiz[d], az);                     \
            ax = fmaf(xv_, win[d], ax); }
            IN3(0,  q0.x) IN3(1,  q0.y) IN3(2,  q0.z) IN3(3,  q0.w)
            IN3(4,  q1.x) IN3(5,  q1.y) IN3(6,  q1.z) IN3(7,  q1.w)
            IN3(8,  q2.x) IN3(9,  q2.y)
            IN3(10, q2.z) IN3(11, q2.w)
            IN3(12, q3.x) IN3(13, q3.y) IN3(14, q3.z) IN3(15, q3.w)
            IN3(16, q4.x) IN3(17, q4.y) IN3(18, q4.z) IN3(19, q4.w)
#undef IN3

            // amv computed this step is for t-1 (broadcasts were h_{t-1});
            // store stays in flight (no vmcnt wait at source level)
            const int t = g * GS + s;
            if (t > 0 && lane < DIN) ob[(size_t)(t - 1) * DIN + lane] = am;

            // nonlinearity (identical numerics to the verified kernel)
            const float r = rcpf(1.0f + __expf(-ar));
            const float z = rcpf(1.0f + __expf(-az));
            const float pre = fmaf(r, ah, ax);
            const float e2 = __expf(2.0f * pre);    // inf-safe: nn -> +/-1
            const float nn = 1.0f - 2.0f * rcpf(e2 + 1.0f);
            h = fmaf(z, h - nn, nn);                // (1-z)*n + z*h
        }
    }

    // epilogue: amv for t = 999 from h_999
    {
        float am = 0.0f;
#pragma unroll
        for (int k = 0; k < HID; ++k) am = fmaf(bcast(h, k), wmv[k], am);
        if (lane < DIN) ob[(size_t)(TT - 1) * DIN + lane] = am;
    }
}

// ---------------- d_out init: the constant term ----------------------------
__global__ void init_out(float* out) {
    // -0.5*NO*T*log(2pi) / (T*NO) = -0.5*log(2pi)
    out[0] = -0.918938533204672742f;
}

// ---------------- Phase 2: per-(n,t) Gaussian log-lik (unchanged) ----------
__global__ __launch_bounds__(256)
void lik_phase2(const float* __restrict__ Yi, const float* __restrict__ Cw,
                const float* __restrict__ Hm, const float* __restrict__ mu_w,
                const float* __restrict__ b_mu, const float* __restrict__ b_var,
                const float* __restrict__ mv_in, float* __restrict__ out) {
    __shared__ float sH[NO * NS];
    __shared__ float smw[NO], sbm[NS], sbv[NS];
    __shared__ float ssum[4];
    const int tid = threadIdx.x;
    if (tid < NO * NS) sH[tid] = Hm[tid];
    if (tid < NO) smw[tid] = mu_w[tid];
    if (tid < NS) { sbm[tid] = b_mu[tid]; sbv[tid] = b_var[tid]; }
    __syncthreads();

    const int gid = blockIdx.x * 256 + tid;   // 0 .. BN*TT-1
    float contrib = 0.0f;
    if (gid < BN * TT) {
        const int n = gid / TT;
        const float* mv = mv_in + (size_t)gid * DIN;
        float mu[NS], va[NS];
#pragma unroll
        for (int i = 0; i < NS; ++i) {
            mu[i] = mv[i] + sbm[i];
            float x = mv[NS + i] + sbv[i];
            va[i] = (x > 0.0f) ? (x + log1pf(__expf(-x))) : log1pf(__expf(x));
        }
        const float* y = Yi + (size_t)gid * NO;
        float e[NO];
#pragma unroll
        for (int i = 0; i < NO; ++i) {
            float m = smw[i];
#pragma unroll
            for (int j = 0; j < NS; ++j) m = fmaf(sH[i * NS + j], mu[j], m);
            e[i] = y[i] - m;
        }
        // M = H diag(va) H^T + Cw (lower triangle only)
        float M[NO][NO];
        const float* cw = Cw + (size_t)n * NO * NO;
#pragma unroll
        for (int i = 0; i < NO; ++i)
#pragma unroll
            for (int j = 0; j <= i; ++j) M[i][j] = cw[i * NO + j];
#pragma unroll
        for (int l = 0; l < NS; ++l) {
            float vl = va[l];
            float hv[NO];
#pragma unroll
            for (int i = 0; i < NO; ++i) hv[i] = sH[i * NS + l];
#pragma unroll
            for (int i = 0; i < NO; ++i) {
                float hvi = hv[i] * vl;
#pragma unroll
                for (int j = 0; j <= i; ++j) M[i][j] = fmaf(hvi, hv[j], M[i][j]);
            }
        }
        // in-place Cholesky (lower); fast rsqrt/rcp (error ~1ulp, harmless
        // vs the 3.1e-2 threshold on an averaged scalar)
        float logdet = 0.0f;
        float drs[NO];                  // 1/sqrt(d_j) for the forward solve
#pragma unroll
        for (int j = 0; j < NO; ++j) {
            float d = M[j][j];
#pragma unroll
            for (int k = 0; k < j; ++k) d = fmaf(-M[j][k], M[j][k], d);
            logdet += __logf(d);
            float rs = __frsqrt_rn(d);
            drs[j] = rs;
            M[j][j] = d * rs;           // sqrt(d)
#pragma unroll
            for (int i = j + 1; i < NO; ++i) {
                float v = M[i][j];
#pragma unroll
                for (int k = 0; k < j; ++k) v = fmaf(-M[i][k], M[j][k], v);
                M[i][j] = v * rs;
            }
        }
        // quad = || L^-1 e ||^2 (forward solve)
        float wv[NO];
        float quad = 0.0f;
#pragma unroll
        for (int i = 0; i < NO; ++i) {
            float v = e[i];
#pragma unroll
            for (int k = 0; k < i; ++k) v = fmaf(-M[i][k], wv[k], v);
            wv[i] = v * drs[i] * rcpf(M[i][i] * drs[i]);  // v / M[i][i]
            quad = fmaf(wv[i], wv[i], quad);
        }
        const float SCALE = 0.5f / ((float)BN * (float)TT * (float)NO);
        contrib = -(logdet + quad) * SCALE;
    }

    // block reduction: wave shuffle, LDS across 4 waves, one atomic
#pragma unroll
    for (int off = 32; off > 0; off >>= 1) contrib += __shfl_down(contrib, off);
    if ((tid & 63) == 0) ssum[tid >> 6] = contrib;
    __syncthreads();
    if (tid == 0) {
        float s = ssum[0] + ssum[1] + ssum[2] + ssum[3];
        atomicAdd(out, s);
    }
}

// ---------------- launch ---------------------------------------------------
extern "C" void kernel_launch(void* const* d_in, const int* in_sizes, int n_in,
                              void* d_out, int out_size, void* d_ws, size_t ws_size,
                              hipStream_t stream) {
    const float* Yi    = (const float*)d_in[0];
    const float* Xh    = (const float*)d_in[1];
    const float* Cw    = (const float*)d_in[2];
    const float* Hm    = (const float*)d_in[3];
    const float* mu_w  = (const float*)d_in[4];
    const float* Wi    = (const float*)d_in[5];
    const float* Wh    = (const float*)d_in[6];
    const float* bi    = (const float*)d_in[7];
    const float* bh    = (const float*)d_in[8];
    const float* W_mu  = (const float*)d_in[9];
    const float* b_mu  = (const float*)d_in[10];
    const float* W_var = (const float*)d_in[11];
    const float* b_var = (const float*)d_in[12];
    float* out = (float*)d_out;
    float* mv  = (float*)d_ws;   // [BN*TT*DIN] floats = 20.48 MB

    init_out<<<1, 1, 0, stream>>>(out);
    gru_onewave<<<dim3(BN), dim3(64), 0, stream>>>(Yi, Xh, Wi, Wh, bi, bh,
                                                   W_mu, W_var, mv);
    lik_phase2<<<dim3((BN * TT + 255) / 256), dim3(256), 0, stream>>>(
        Yi, Cw, Hm, mu_w, b_mu, b_var, mv, out);
}

// Round 2
// 758.876 us; speedup vs baseline: 1.4024x; 1.4024x over previous
//
#include <hip/hip_runtime.h>
#include <math.h>

// Problem constants (fixed by the reference)
#define BN 256     // batch N
#define TT 1000    // timesteps
#define NO 10      // obs dim
#define NS 10      // state dim
#define HID 64     // GRU hidden == wavefront size
#define DIN 20     // NO + NS
#define G3 192     // 3*HID
#define GS 8       // steps per input group (1000 = 125 * 8)
#define NG 125     // groups
#define KW 32      // k-range per wave (2 waves)

// broadcast lane `l`'s value of v to all lanes (l wave-uniform)
__device__ __forceinline__ float bcast(float v, int l) {
    return __int_as_float(__builtin_amdgcn_readlane(__float_as_int(v), l));
}
__device__ __forceinline__ float rcpf(float x) { return __builtin_amdgcn_rcpf(x); }

// Workgroup barrier WITHOUT the vmcnt(0) drain __syncthreads() emits.
// LDS ordering needs only lgkmcnt(0); global loads/stores issued before the
// barrier stay in flight.
__device__ __forceinline__ void sync_lds() {
    asm volatile("s_waitcnt lgkmcnt(0)\n\ts_barrier" ::: "memory");
}

// ---------------- Phase 1: GRU recurrence, TWO WAVES PER SAMPLE ------------
// R7: bracketing from R5/R6 measurements:
//   4-wave k-split = 1240 cy/step (~280 issue + ~950 sync: 4x b128 read burst)
//   1-wave         = 2310 cy/step (register-infeasible: 350 VGPR demand > 256
//                    addressable -> AGPR parking, ~600 accvgpr_read/step)
// 2-wave k-split: per-lane weights 4*32+3*10 = 158 -> ~210 VGPR, register-
// resident. Exchange shrinks to ONE ds_write_b128 + barrier + ONE
// ds_read_b128 (partner partials). Both waves redundantly run the
// nonlinearity so each holds full h for its own readlane broadcasts.
__global__
__attribute__((amdgpu_flat_work_group_size(128, 128), amdgpu_waves_per_eu(1, 1)))
void gru_2wave(const float* __restrict__ Yi, const float* __restrict__ Xh,
               const float* __restrict__ Wi, const float* __restrict__ Wh,
               const float* __restrict__ bi, const float* __restrict__ bh,
               const float* __restrict__ Wmu, const float* __restrict__ Wvar,
               float* __restrict__ mv_out) {
    const int tid = threadIdx.x;
    const int lane = tid & 63;      // hidden unit index
    const int w = tid >> 6;         // wave id 0..1
    const int kb = w * KW;          // this wave's k-range base

    // partial exchange: [buf][wave][lane] = {r, z, nx, nh}   (4 KB)
    __shared__ float4 part[2][2][HID];
    // amv partials from wave 0 (wave 1 reads, adds own, stores) (512 B)
    __shared__ float pamv[2][HID];
    // input staging: [buf][step][32]: y at +0..9, x at +16..25 (2 KB)
    __shared__ __align__(16) float inb[2][GS * 32];

    const int n = blockIdx.x;
    const float* yb = Yi + (size_t)n * TT * NO;
    const float* xb = Xh + (size_t)n * TT * NS;
    float* ob = mv_out + (size_t)n * TT * DIN;

    // ---- per-lane weight slices (register-resident) ----
    float whr[KW], whz[KW], whn[KW], wmv[KW];
#pragma unroll
    for (int k = 0; k < KW; ++k) {
        const int kk = kb + k;
        whr[k] = Wh[kk * G3 + lane];
        whz[k] = Wh[kk * G3 + 64 + lane];
        whn[k] = Wh[kk * G3 + 128 + lane];
        float wm = 0.0f;
        if (lane < NS) wm = Wmu[kk * NS + lane];
        else if (lane < DIN) wm = Wvar[kk * NS + (lane - NS)];
        wmv[k] = wm;    // packed: lanes 0..9 -> W_mu, lanes 10..19 -> W_var
    }
    float wir[10], wiz[10], win[10];
    const int d0 = 10 * w;          // wave's 10 input dims
#pragma unroll
    for (int j = 0; j < 10; ++j) {
        wir[j] = Wi[(d0 + j) * G3 + lane];
        wiz[j] = Wi[(d0 + j) * G3 + 64 + lane];
        win[j] = Wi[(d0 + j) * G3 + 128 + lane];
    }
    const float b_r  = bi[lane] + bh[lane];
    const float b_z  = bi[64 + lane] + bh[64 + lane];
    const float bx_n = bi[128 + lane];
    const float bh_n = bh[128 + lane];

    // staging map: thread stages flat input f0 (y if tid<80, else x f=tid-80)
    // and, for tid<32, x f1 = 48+tid. Slot layout: step*32 + (y?0:16) + dim.
    const bool isy0 = tid < 80;
    const int f0 = isy0 ? tid : tid - 80;
    const int slot0 = (f0 / 10) * 32 + (isy0 ? 0 : 16) + (f0 % 10);
    const int f1 = 48 + tid;
    const int slot1 = (f1 / 10) * 32 + 16 + (f1 % 10);

    // prologue: stage group 0
    {
        float a = isy0 ? yb[f0] : xb[f0];
        inb[0][slot0] = a;
        if (tid < 32) inb[0][slot1] = xb[f1];
    }
    sync_lds();

    float h = 0.0f;

#pragma unroll 1
    for (int g = 0; g < NG; ++g) {
        // prefetch next group into regs; 8 steps of latency cover
        float ld0 = 0.0f, ld1 = 0.0f;
        const bool do_ld = (g + 1 < NG);
        if (do_ld) {
            const size_t o = (size_t)(g + 1) * 80;
            ld0 = isy0 ? yb[o + f0] : xb[o + f0];
            if (tid < 32) ld1 = xb[o + f1];
        }
        const float* ib = inb[g & 1] + 16 * w;   // wave's dim base in a row

#pragma unroll
        for (int s = 0; s < GS; ++s) {
            // ---- pre-barrier: this wave's partials (t = 8g+s, h = h_{t-1}) --
            // input projection: 10 dims, broadcast reads (same addr all lanes)
            const float4* qp = (const float4*)(ib + 32 * s);
            const float4 q0 = qp[0], q1 = qp[1], q2 = qp[2];  // 10 used
            float xr = q0.x * wir[0], xz = q0.x * wiz[0], xn = q0.x * win[0];
            xr = fmaf(q0.y, wir[1], xr); xz = fmaf(q0.y, wiz[1], xz); xn = fmaf(q0.y, win[1], xn);
            xr = fmaf(q0.z, wir[2], xr); xz = fmaf(q0.z, wiz[2], xz); xn = fmaf(q0.z, win[2], xn);
            xr = fmaf(q0.w, wir[3], xr); xz = fmaf(q0.w, wiz[3], xz); xn = fmaf(q0.w, win[3], xn);
            xr = fmaf(q1.x, wir[4], xr); xz = fmaf(q1.x, wiz[4], xz); xn = fmaf(q1.x, win[4], xn);
            xr = fmaf(q1.y, wir[5], xr); xz = fmaf(q1.y, wiz[5], xz); xn = fmaf(q1.y, win[5], xn);
            xr = fmaf(q1.z, wir[6], xr); xz = fmaf(q1.z, wiz[6], xz); xn = fmaf(q1.z, win[6], xn);
            xr = fmaf(q1.w, wir[7], xr); xz = fmaf(q1.w, wiz[7], xz); xn = fmaf(q1.w, win[7], xn);
            xr = fmaf(q2.x, wir[8], xr); xz = fmaf(q2.x, wiz[8], xz); xn = fmaf(q2.x, win[8], xn);
            xr = fmaf(q2.y, wir[9], xr); xz = fmaf(q2.y, wiz[9], xz); xn = fmaf(q2.y, win[9], xn);

            // hidden projection over this wave's 32 k's
            float pr = 0.0f, pz = 0.0f, pn = 0.0f, pm = 0.0f;
#pragma unroll
            for (int k = 0; k < KW; ++k) {
                const float hv = bcast(h, kb + k);
                pr = fmaf(hv, whr[k], pr);
                pz = fmaf(hv, whz[k], pz);
                pn = fmaf(hv, whn[k], pn);
                pm = fmaf(hv, wmv[k], pm);
            }
            const int bp = s & 1;
            part[bp][w][lane] = make_float4(pr + xr, pz + xz, xn, pn);
            if (w == 0) pamv[bp][lane] = pm;
            // stage next group just before the group's last barrier
            if (s == GS - 1 && do_ld) {
                inb[(g + 1) & 1][slot0] = ld0;
                if (tid < 32) inb[(g + 1) & 1][slot1] = ld1;
            }
            sync_lds();

            // ---- post-barrier: one b128 read of partner partials ----
            const float4 o = part[bp][w ^ 1][lane];
            const float ar = b_r  + (pr + xr) + o.x;
            const float az = b_z  + (pz + xz) + o.y;
            const float ax = bx_n + xn + o.z;
            const float ah = bh_n + pn + o.w;
            if (w == 1) {   // amv for output t-1 (fire-and-forget store)
                const int t = g * GS + s;
                const float am = pm + pamv[bp][lane];
                if (t > 0 && lane < DIN)
                    ob[(size_t)(t - 1) * DIN + lane] = am;
            }

            // nonlinearity (identical numerics to the verified kernel)
            const float r = rcpf(1.0f + __expf(-ar));
            const float z = rcpf(1.0f + __expf(-az));
            const float pre = fmaf(r, ah, ax);
            const float e2 = __expf(2.0f * pre);   // inf-safe: nn -> +/-1
            const float nn = 1.0f - 2.0f * rcpf(e2 + 1.0f);
            h = fmaf(z, h - nn, nn);               // (1-z)*n + z*h
        }
    }

    // epilogue: amv for t = 999 from h_999
    {
        float pm = 0.0f;
#pragma unroll
        for (int k = 0; k < KW; ++k) pm = fmaf(bcast(h, kb + k), wmv[k], pm);
        if (w == 0) pamv[0][lane] = pm;
        sync_lds();
        if (w == 1 && lane < DIN)
            ob[(size_t)(TT - 1) * DIN + lane] = pm + pamv[0][lane];
    }
}

// ---------------- d_out init: the constant term ----------------------------
__global__ void init_out(float* out) {
    // -0.5*NO*T*log(2pi) / (T*NO) = -0.5*log(2pi)
    out[0] = -0.918938533204672742f;
}

// ---------------- Phase 2: per-(n,t) Gaussian log-lik (unchanged) ----------
__global__ __launch_bounds__(256)
void lik_phase2(const float* __restrict__ Yi, const float* __restrict__ Cw,
                const float* __restrict__ Hm, const float* __restrict__ mu_w,
                const float* __restrict__ b_mu, const float* __restrict__ b_var,
                const float* __restrict__ mv_in, float* __restrict__ out) {
    __shared__ float sH[NO * NS];
    __shared__ float smw[NO], sbm[NS], sbv[NS];
    __shared__ float ssum[4];
    const int tid = threadIdx.x;
    if (tid < NO * NS) sH[tid] = Hm[tid];
    if (tid < NO) smw[tid] = mu_w[tid];
    if (tid < NS) { sbm[tid] = b_mu[tid]; sbv[tid] = b_var[tid]; }
    __syncthreads();

    const int gid = blockIdx.x * 256 + tid;   // 0 .. BN*TT-1
    float contrib = 0.0f;
    if (gid < BN * TT) {
        const int n = gid / TT;
        const float* mv = mv_in + (size_t)gid * DIN;
        float mu[NS], va[NS];
#pragma unroll
        for (int i = 0; i < NS; ++i) {
            mu[i] = mv[i] + sbm[i];
            float x = mv[NS + i] + sbv[i];
            va[i] = (x > 0.0f) ? (x + log1pf(__expf(-x))) : log1pf(__expf(x));
        }
        const float* y = Yi + (size_t)gid * NO;
        float e[NO];
#pragma unroll
        for (int i = 0; i < NO; ++i) {
            float m = smw[i];
#pragma unroll
            for (int j = 0; j < NS; ++j) m = fmaf(sH[i * NS + j], mu[j], m);
            e[i] = y[i] - m;
        }
        // M = H diag(va) H^T + Cw (lower triangle only)
        float M[NO][NO];
        const float* cw = Cw + (size_t)n * NO * NO;
#pragma unroll
        for (int i = 0; i < NO; ++i)
#pragma unroll
            for (int j = 0; j <= i; ++j) M[i][j] = cw[i * NO + j];
#pragma unroll
        for (int l = 0; l < NS; ++l) {
            float vl = va[l];
            float hv[NO];
#pragma unroll
            for (int i = 0; i < NO; ++i) hv[i] = sH[i * NS + l];
#pragma unroll
            for (int i = 0; i < NO; ++i) {
                float hvi = hv[i] * vl;
#pragma unroll
                for (int j = 0; j <= i; ++j) M[i][j] = fmaf(hvi, hv[j], M[i][j]);
            }
        }
        // in-place Cholesky (lower); fast rsqrt/rcp (error ~1ulp, harmless
        // vs the 3.1e-2 threshold on an averaged scalar)
        float logdet = 0.0f;
        float drs[NO];                  // 1/sqrt(d_j) for the forward solve
#pragma unroll
        for (int j = 0; j < NO; ++j) {
            float d = M[j][j];
#pragma unroll
            for (int k = 0; k < j; ++k) d = fmaf(-M[j][k], M[j][k], d);
            logdet += __logf(d);
            float rs = __frsqrt_rn(d);
            drs[j] = rs;
            M[j][j] = d * rs;           // sqrt(d)
#pragma unroll
            for (int i = j + 1; i < NO; ++i) {
                float v = M[i][j];
#pragma unroll
                for (int k = 0; k < j; ++k) v = fmaf(-M[i][k], M[j][k], v);
                M[i][j] = v * rs;
            }
        }
        // quad = || L^-1 e ||^2 (forward solve)
        float wv[NO];
        float quad = 0.0f;
#pragma unroll
        for (int i = 0; i < NO; ++i) {
            float v = e[i];
#pragma unroll
            for (int k = 0; k < i; ++k) v = fmaf(-M[i][k], wv[k], v);
            wv[i] = v * drs[i] * rcpf(M[i][i] * drs[i]);  // v / M[i][i]
            quad = fmaf(wv[i], wv[i], quad);
        }
        const float SCALE = 0.5f / ((float)BN * (float)TT * (float)NO);
        contrib = -(logdet + quad) * SCALE;
    }

    // block reduction: wave shuffle, LDS across 4 waves, one atomic
#pragma unroll
    for (int off = 32; off > 0; off >>= 1) contrib += __shfl_down(contrib, off);
    if ((tid & 63) == 0) ssum[tid >> 6] = contrib;
    __syncthreads();
    if (tid == 0) {
        float s = ssum[0] + ssum[1] + ssum[2] + ssum[3];
        atomicAdd(out, s);
    }
}

// ---------------- launch ---------------------------------------------------
extern "C" void kernel_launch(void* const* d_in, const int* in_sizes, int n_in,
                              void* d_out, int out_size, void* d_ws, size_t ws_size,
                              hipStream_t stream) {
    const float* Yi    = (const float*)d_in[0];
    const float* Xh    = (const float*)d_in[1];
    const float* Cw    = (const float*)d_in[2];
    const float* Hm    = (const float*)d_in[3];
    const float* mu_w  = (const float*)d_in[4];
    const float* Wi    = (const float*)d_in[5];
    const float* Wh    = (const float*)d_in[6];
    const float* bi    = (const float*)d_in[7];
    const float* bh    = (const float*)d_in[8];
    const float* W_mu  = (const float*)d_in[9];
    const float* b_mu  = (const float*)d_in[10];
    const float* W_var = (const float*)d_in[11];
    const float* b_var = (const float*)d_in[12];
    float* out = (float*)d_out;
    float* mv  = (float*)d_ws;   // [BN*TT*DIN] floats = 20.48 MB

    init_out<<<1, 1, 0, stream>>>(out);
    gru_2wave<<<dim3(BN), dim3(128), 0, stream>>>(Yi, Xh, Wi, Wh, bi, bh,
                                                  W_mu, W_var, mv);
    lik_phase2<<<dim3((BN * TT + 255) / 256), dim3(256), 0, stream>>>(
        Yi, Cw, Hm, mu_w, b_mu, b_var, mv, out);
}